// Round 2
// baseline (508.201 us; speedup 1.0000x reference)
//
#include <hip/hip_runtime.h>

#define Bn 16384
#define Hn 128
#define Gn 5
#define Tn 12

typedef __attribute__((ext_vector_type(8))) __bf16 bf16x8;
typedef __attribute__((ext_vector_type(4))) float f32x4;
typedef __attribute__((ext_vector_type(4))) unsigned int u32x4;
typedef __attribute__((ext_vector_type(2))) unsigned int u32x2;
typedef unsigned int u32;
typedef unsigned short u16;

#define MFMA(a, b, c) __builtin_amdgcn_mfma_f32_16x16x32_bf16((a), (b), (c), 0, 0, 0)

__device__ __forceinline__ u16 f2bf(float f) { return __builtin_bit_cast(u16, (__bf16)f); }
__device__ __forceinline__ float bf2f(u16 h) { u32 u = ((u32)h) << 16; return __builtin_bit_cast(float, u); }
__device__ __forceinline__ float sigf(float x) {
    return __builtin_amdgcn_rcpf(1.0f + __builtin_amdgcn_exp2f(-1.44269504f * x));
}
__device__ __forceinline__ float tanhf_(float x) {
    return 1.0f - 2.0f * __builtin_amdgcn_rcpf(1.0f + __builtin_amdgcn_exp2f(2.88539008f * x));
}

// Swizzled byte offsets (chunk-XOR): [rows][128] bf16 tile, 256 B rows, 16 chunks of 16 B
__device__ __forceinline__ int hbsw(int row, int bytein) {
    return row * 256 + ((((bytein >> 4) ^ row) & 15) << 4) + (bytein & 15);
}
// [rows][64] bf16 tile: 128 B rows, 8 chunks
__device__ __forceinline__ int pbsw(int row, int bytein) {
    return row * 128 + ((((bytein >> 4) ^ row) & 7) << 4) + (bytein & 15);
}

// ---------------- Kernel 1: goals + goal_probs (phase A) ----------------
__global__ __launch_bounds__(256) void k_phaseA(
    const float* __restrict__ eh, const float* __restrict__ lastpos,
    const float* __restrict__ gp_w1, const float* __restrict__ gp_b1,
    const float* __restrict__ gp_w2, const float* __restrict__ gp_b2,
    const float* __restrict__ pr_w1, const float* __restrict__ pr_b1,
    const float* __restrict__ pr_w2, const float* __restrict__ pr_b2,
    float* __restrict__ goals_o, float* __restrict__ probs_o)
{
    __shared__ __align__(16) char eT[64 * 256];  // [64][128] bf16
    __shared__ __align__(16) char gT[64 * 256];  // [64][128] bf16
    __shared__ __align__(16) char pT[64 * 128];  // [64][64] bf16
    __shared__ float lgT[64 * 8];

    const int tid = threadIdx.x;
    const int lane = tid & 63;
    const int wv = tid >> 6;           // 0..3
    const int lg = lane >> 4, li = lane & 15;
    const int r0 = blockIdx.x * 64;
    const int rowbase = wv * 16;

    // stage eh -> bf16 LDS (swizzled)
    {
        int row = tid >> 2, seg = tid & 3;
        const float* src = eh + (size_t)(r0 + row) * Hn + seg * 32;
#pragma unroll
        for (int cc = 0; cc < 4; ++cc) {
            u32 p0 = (u32)f2bf(src[cc * 8 + 0]) | ((u32)f2bf(src[cc * 8 + 1]) << 16);
            u32 p1 = (u32)f2bf(src[cc * 8 + 2]) | ((u32)f2bf(src[cc * 8 + 3]) << 16);
            u32 p2 = (u32)f2bf(src[cc * 8 + 4]) | ((u32)f2bf(src[cc * 8 + 5]) << 16);
            u32 p3 = (u32)f2bf(src[cc * 8 + 6]) | ((u32)f2bf(src[cc * 8 + 7]) << 16);
            *(u32x4*)(eT + hbsw(row, seg * 64 + cc * 16)) = (u32x4){p0, p1, p2, p3};
        }
    }
    __syncthreads();

    bf16x8 Ae[4];
#pragma unroll
    for (int kc = 0; kc < 4; ++kc)
        Ae[kc] = *(const bf16x8*)(eT + hbsw(rowbase + li, kc * 64 + lg * 16));

    // g_hid = relu(eh @ gp_w1 + gp_b1)
#pragma unroll 1
    for (int nt = 0; nt < 8; ++nt) {
        int c1 = nt * 16 + li;
        f32x4 acc = {0.f, 0.f, 0.f, 0.f};
#pragma unroll
        for (int kc = 0; kc < 4; ++kc) {
            bf16x8 bfr;
#pragma unroll
            for (int j = 0; j < 8; ++j)
                bfr[j] = (__bf16)gp_w1[(size_t)(kc * 32 + lg * 8 + j) * Hn + c1];
            acc = MFMA(Ae[kc], bfr, acc);
        }
        float bias = gp_b1[c1];
#pragma unroll
        for (int r = 0; r < 4; ++r) {
            int row = rowbase + lg * 4 + r;
            float v = fmaxf(acc[r] + bias, 0.f);
            *(u16*)(gT + hbsw(row, c1 * 2)) = f2bf(v);
        }
    }
    __syncthreads();

    // goals = g_hid @ gp_w2 + gp_b2 + last_pos
    {
        bf16x8 Ag[4];
#pragma unroll
        for (int kc = 0; kc < 4; ++kc)
            Ag[kc] = *(const bf16x8*)(gT + hbsw(rowbase + li, kc * 64 + lg * 16));
        f32x4 acc = {0.f, 0.f, 0.f, 0.f};
#pragma unroll
        for (int kc = 0; kc < 4; ++kc) {
            bf16x8 bfr;
#pragma unroll
            for (int j = 0; j < 8; ++j) {
                int k = kc * 32 + lg * 8 + j;
                bfr[j] = (li < 10) ? (__bf16)gp_w2[k * 10 + li] : (__bf16)0.f;
            }
            acc = MFMA(Ag[kc], bfr, acc);
        }
        if (li < 10) {
            float b2 = gp_b2[li];
#pragma unroll
            for (int r = 0; r < 4; ++r) {
                int b = r0 + rowbase + lg * 4 + r;
                float v = acc[r] + b2 + lastpos[(size_t)b * 2 + (li & 1)];
                goals_o[(size_t)b * 10 + li] = v;
            }
        }
    }

    // p_hid = relu(eh @ pr_w1 + pr_b1)
#pragma unroll 1
    for (int nt = 0; nt < 4; ++nt) {
        int c1 = nt * 16 + li;
        f32x4 acc = {0.f, 0.f, 0.f, 0.f};
#pragma unroll
        for (int kc = 0; kc < 4; ++kc) {
            bf16x8 bfr;
#pragma unroll
            for (int j = 0; j < 8; ++j)
                bfr[j] = (__bf16)pr_w1[(size_t)(kc * 32 + lg * 8 + j) * 64 + c1];
            acc = MFMA(Ae[kc], bfr, acc);
        }
        float bias = pr_b1[c1];
#pragma unroll
        for (int r = 0; r < 4; ++r) {
            int row = rowbase + lg * 4 + r;
            float v = fmaxf(acc[r] + bias, 0.f);
            *(u16*)(pT + pbsw(row, c1 * 2)) = f2bf(v);
        }
    }
    __syncthreads();

    // logits = p_hid @ pr_w2 + pr_b2
    {
        bf16x8 Ap[2];
#pragma unroll
        for (int kc = 0; kc < 2; ++kc)
            Ap[kc] = *(const bf16x8*)(pT + pbsw(rowbase + li, kc * 64 + lg * 16));
        f32x4 acc = {0.f, 0.f, 0.f, 0.f};
#pragma unroll
        for (int kc = 0; kc < 2; ++kc) {
            bf16x8 bfr;
#pragma unroll
            for (int j = 0; j < 8; ++j) {
                int k = kc * 32 + lg * 8 + j;
                bfr[j] = (li < 5) ? (__bf16)pr_w2[k * 5 + li] : (__bf16)0.f;
            }
            acc = MFMA(Ap[kc], bfr, acc);
        }
        if (li < 5) {
            float b2 = pr_b2[li];
#pragma unroll
            for (int r = 0; r < 4; ++r) {
                int row = rowbase + lg * 4 + r;
                lgT[row * 8 + li] = acc[r] + b2;
            }
        }
    }
    __syncthreads();

    if (tid < 64) {
        int row = tid;
        float v0 = lgT[row * 8 + 0], v1 = lgT[row * 8 + 1], v2 = lgT[row * 8 + 2];
        float v3 = lgT[row * 8 + 3], v4 = lgT[row * 8 + 4];
        float mx = fmaxf(fmaxf(fmaxf(v0, v1), fmaxf(v2, v3)), v4);
        float e0 = __builtin_amdgcn_exp2f((v0 - mx) * 1.44269504f);
        float e1 = __builtin_amdgcn_exp2f((v1 - mx) * 1.44269504f);
        float e2 = __builtin_amdgcn_exp2f((v2 - mx) * 1.44269504f);
        float e3 = __builtin_amdgcn_exp2f((v3 - mx) * 1.44269504f);
        float e4 = __builtin_amdgcn_exp2f((v4 - mx) * 1.44269504f);
        float rs = __builtin_amdgcn_rcpf(e0 + e1 + e2 + e3 + e4);
        size_t ob = (size_t)(r0 + row) * 5;
        probs_o[ob + 0] = e0 * rs;
        probs_o[ob + 1] = e1 * rs;
        probs_o[ob + 2] = e2 * rs;
        probs_o[ob + 3] = e3 * rs;
        probs_o[ob + 4] = e4 * rs;
    }
}

// ---------------- Kernel 2: LSTM rollout (swapped-operand MFMA) ----------------
// 64 rows per workgroup, 512 threads (8 waves). Wave wv owns hidden cols
// [wv*16, wv*16+16) for all 4 gates. gates^T = mfma(W_frag, H_frag):
// acc col = lane&15 = batch row, acc row = lg*4+r = hidden-col offset
// -> h_new write is 4 consecutive bf16 per thread: one ds_write_b64, conflict-free.
__global__ __launch_bounds__(512, 4) void k_lstm(
    const float* __restrict__ eh, const float* __restrict__ ec,
    const float* __restrict__ lastpos,
    const float* __restrict__ w_ih, const float* __restrict__ w_hh,
    const float* __restrict__ b_ih, const float* __restrict__ b_hh,
    const float* __restrict__ ph_w, const float* __restrict__ ph_b,
    const float* __restrict__ goals_o, float* __restrict__ preds)
{
    __shared__ __align__(16) char hT[2][64 * 256];  // double-buffered [64][128] bf16, swizzled
    __shared__ float pos2[64 * 2];
    __shared__ float phwl[256];

    const int tid = threadIdx.x;
    const int lane = tid & 63;
    const int wv = tid >> 6;            // 0..7
    const int lg = lane >> 4, li = lane & 15;
    const int r0 = blockIdx.x * 64;

    // --- weight fragments in registers (A-operand form; same per-lane data as B-form)
    bf16x8 Wh[4][4];   // w_hh, [gate][kc]
    bf16x8 Wx[4];      // [w_ih; b_ih+b_hh; 0...], K=32
#pragma unroll
    for (int gt = 0; gt < 4; ++gt) {
        const int cg = gt * 128 + wv * 16 + li;
#pragma unroll
        for (int kc = 0; kc < 4; ++kc) {
            bf16x8 f;
#pragma unroll
            for (int j = 0; j < 8; ++j)
                f[j] = (__bf16)w_hh[(size_t)(kc * 32 + lg * 8 + j) * 512 + cg];
            Wh[gt][kc] = f;
        }
        bf16x8 fx;
#pragma unroll
        for (int j = 0; j < 8; ++j) {
            int k = lg * 8 + j;
            float v = 0.f;
            if (k < 4) v = w_ih[k * 512 + cg];
            else if (k == 4) v = b_ih[cg] + b_hh[cg];
            fx[j] = (__bf16)v;
        }
        Wx[gt] = fx;
    }

    // --- goals packed per m-tile (bf16 pair), for in-register x-fragment
    u32 gpk[4];
#pragma unroll
    for (int m = 0; m < 4; ++m) {
        int gr = r0 + m * 16 + li;
        float2 g2 = *(const float2*)(goals_o + (size_t)gr * 2);
        gpk[m] = (u32)f2bf(g2.x) | ((u32)f2bf(g2.y) << 16);
    }

    // --- stage h0 = encoder_hidden (broadcast over g) into buffer 0
    {
        int row = tid >> 3, seg = tid & 7;
        int b = (r0 + row) / 5;
        const float* src = eh + (size_t)b * Hn + seg * 16;
#pragma unroll
        for (int cp = 0; cp < 2; ++cp) {
            u32 p0 = (u32)f2bf(src[cp * 8 + 0]) | ((u32)f2bf(src[cp * 8 + 1]) << 16);
            u32 p1 = (u32)f2bf(src[cp * 8 + 2]) | ((u32)f2bf(src[cp * 8 + 3]) << 16);
            u32 p2 = (u32)f2bf(src[cp * 8 + 4]) | ((u32)f2bf(src[cp * 8 + 5]) << 16);
            u32 p3 = (u32)f2bf(src[cp * 8 + 6]) | ((u32)f2bf(src[cp * 8 + 7]) << 16);
            *(u32x4*)(hT[0] + hbsw(row, seg * 32 + cp * 16)) = (u32x4){p0, p1, p2, p3};
        }
    }
    // --- pos master copy + ph_w staging
    if (tid < 64) {
        int b = (r0 + tid) / 5;
        float2 p = *(const float2*)(lastpos + (size_t)b * 2);
        pos2[2 * tid] = p.x;
        pos2[2 * tid + 1] = p.y;
    }
    if (tid < 256) phwl[tid] = ph_w[tid];
    const float phb0 = ph_b[0], phb1 = ph_b[1];

    // --- c0 registers (f32 master): c[m][r] at (batch m*16+li, hidden col wv*16+lg*4+r)
    float c[4][4];
#pragma unroll
    for (int m = 0; m < 4; ++m) {
        int b = (r0 + m * 16 + li) / 5;
        float4 cv = *(const float4*)(ec + (size_t)b * Hn + wv * 16 + lg * 4);
        c[m][0] = cv.x; c[m][1] = cv.y; c[m][2] = cv.z; c[m][3] = cv.w;
    }

    __syncthreads();

#pragma unroll 1
    for (int t = 0; t < Tn; ++t) {
        const char* rb = hT[t & 1];
        char* wb = hT[(t & 1) ^ 1];
#pragma unroll
        for (int m = 0; m < 4; ++m) {
            // x-fragment in registers (B-operand; nonzero only for lg==0)
            float2 p2 = *(const float2*)(&pos2[(m * 16 + li) * 2]);
            u32 xw0 = (lg == 0) ? ((u32)f2bf(p2.x) | ((u32)f2bf(p2.y) << 16)) : 0u;
            u32 xw1 = (lg == 0) ? gpk[m] : 0u;
            u32 xw2 = (lg == 0) ? 0x00003F80u : 0u;   // bf16 1.0 at k=4 (bias row)
            bf16x8 xf = __builtin_bit_cast(bf16x8, (u32x4){xw0, xw1, xw2, 0u});

            f32x4 a0 = {0.f, 0.f, 0.f, 0.f}, a1 = {0.f, 0.f, 0.f, 0.f};
            f32x4 a2 = {0.f, 0.f, 0.f, 0.f}, a3 = {0.f, 0.f, 0.f, 0.f};
#pragma unroll
            for (int kc = 0; kc < 4; ++kc) {
                bf16x8 Hf = *(const bf16x8*)(rb + hbsw(m * 16 + li, kc * 64 + lg * 16));
                a0 = MFMA(Wh[0][kc], Hf, a0);
                a1 = MFMA(Wh[1][kc], Hf, a1);
                a2 = MFMA(Wh[2][kc], Hf, a2);
                a3 = MFMA(Wh[3][kc], Hf, a3);
            }
            a0 = MFMA(Wx[0], xf, a0);
            a1 = MFMA(Wx[1], xf, a1);
            a2 = MFMA(Wx[2], xf, a2);
            a3 = MFMA(Wx[3], xf, a3);

            u32 w0 = 0, w1 = 0;
#pragma unroll
            for (int r = 0; r < 4; ++r) {
                float cn = sigf(a1[r]) * c[m][r] + sigf(a0[r]) * tanhf_(a2[r]);
                c[m][r] = cn;
                float hv = sigf(a3[r]) * tanhf_(cn);
                u32 hb = (u32)f2bf(hv);
                if (r == 0) w0 = hb;
                else if (r == 1) w0 |= hb << 16;
                else if (r == 2) w1 = hb;
                else w1 |= hb << 16;
            }
            // one contiguous 8B write: row = m*16+li, cols wv*16+lg*4 .. +3
            *(u32x2*)(wb + hbsw(m * 16 + li, wv * 32 + lg * 8)) = (u32x2){w0, w1};
        }
        __syncthreads();   // h_new visible (and old-h reads complete for next write)

        // --- pos update: pos += h_new @ ph_w + ph_b
        {
            int row = tid >> 3, seg = tid & 7;
            float sx = 0.f, sy = 0.f;
#pragma unroll
            for (int cp = 0; cp < 2; ++cp) {
                u32x4 d = *(const u32x4*)(wb + hbsw(row, seg * 32 + cp * 16));
                int cb = seg * 16 + cp * 8;
#pragma unroll
                for (int j = 0; j < 4; ++j) {
                    float h0 = bf2f((u16)(d[j] & 0xFFFFu));
                    float h1 = bf2f((u16)(d[j] >> 16));
                    int cidx = cb + 2 * j;
                    sx += h0 * phwl[cidx * 2 + 0] + h1 * phwl[cidx * 2 + 2];
                    sy += h0 * phwl[cidx * 2 + 1] + h1 * phwl[cidx * 2 + 3];
                }
            }
            sx += __shfl_xor(sx, 1); sy += __shfl_xor(sy, 1);
            sx += __shfl_xor(sx, 2); sy += __shfl_xor(sy, 2);
            sx += __shfl_xor(sx, 4); sy += __shfl_xor(sy, 4);
            if (seg == 0) {
                float px = pos2[2 * row] + sx + phb0;
                float py = pos2[2 * row + 1] + sy + phb1;
                pos2[2 * row] = px;
                pos2[2 * row + 1] = py;
                size_t o = ((size_t)(r0 + row) * Tn + t) * 2;
                *(float2*)(preds + o) = make_float2(px, py);
            }
        }
        __syncthreads();   // pos2 visible for next step's x-fragment
    }
}

extern "C" void kernel_launch(void* const* d_in, const int* in_sizes, int n_in,
                              void* d_out, int out_size, void* d_ws, size_t ws_size,
                              hipStream_t stream)
{
    (void)in_sizes; (void)n_in; (void)out_size; (void)d_ws; (void)ws_size;
    const float* eh   = (const float*)d_in[0];
    const float* ec   = (const float*)d_in[1];
    const float* lp   = (const float*)d_in[2];
    const float* gpw1 = (const float*)d_in[3];
    const float* gpb1 = (const float*)d_in[4];
    const float* gpw2 = (const float*)d_in[5];
    const float* gpb2 = (const float*)d_in[6];
    const float* prw1 = (const float*)d_in[7];
    const float* prb1 = (const float*)d_in[8];
    const float* prw2 = (const float*)d_in[9];
    const float* prb2 = (const float*)d_in[10];
    const float* wih  = (const float*)d_in[11];
    const float* whh  = (const float*)d_in[12];
    const float* bih  = (const float*)d_in[13];
    const float* bhh  = (const float*)d_in[14];
    const float* phw  = (const float*)d_in[15];
    const float* phb  = (const float*)d_in[16];

    float* out = (float*)d_out;
    float* preds = out;                                            // [B,G,T,2]
    float* goals = out + (size_t)Bn * Gn * Tn * 2;                 // [B,G,2]
    float* probs = out + (size_t)Bn * Gn * Tn * 2 + (size_t)Bn * Gn * 2;  // [B,G]

    k_phaseA<<<Bn / 64, 256, 0, stream>>>(eh, lp, gpw1, gpb1, gpw2, gpb2,
                                          prw1, prb1, prw2, prb2, goals, probs);
    k_lstm<<<(Bn * Gn) / 64, 512, 0, stream>>>(eh, ec, lp, wih, whh, bih, bhh,
                                               phw, phb, goals, preds);
}

// Round 3
// 376.280 us; speedup vs baseline: 1.3506x; 1.3506x over previous
//
#include <hip/hip_runtime.h>

#define Bn 16384
#define Hn 128
#define Gn 5
#define Tn 12

typedef __attribute__((ext_vector_type(8))) __bf16 bf16x8;
typedef __attribute__((ext_vector_type(4))) float f32x4;
typedef __attribute__((ext_vector_type(4))) unsigned int u32x4;
typedef __attribute__((ext_vector_type(2))) unsigned int u32x2;
typedef unsigned int u32;
typedef unsigned short u16;

#define MFMA(a, b, c) __builtin_amdgcn_mfma_f32_16x16x32_bf16((a), (b), (c), 0, 0, 0)

__device__ __forceinline__ u16 f2bf(float f) { return __builtin_bit_cast(u16, (__bf16)f); }
__device__ __forceinline__ float bf2f(u16 h) { u32 u = ((u32)h) << 16; return __builtin_bit_cast(float, u); }
__device__ __forceinline__ float sigf(float x) {
    return __builtin_amdgcn_rcpf(1.0f + __builtin_amdgcn_exp2f(-1.44269504f * x));
}
__device__ __forceinline__ float tanhf_(float x) {
    return 1.0f - 2.0f * __builtin_amdgcn_rcpf(1.0f + __builtin_amdgcn_exp2f(2.88539008f * x));
}

// Swizzled byte offsets (chunk-XOR): [rows][128] bf16 tile, 256 B rows, 16 chunks of 16 B
__device__ __forceinline__ int hbsw(int row, int bytein) {
    return row * 256 + ((((bytein >> 4) ^ row) & 15) << 4) + (bytein & 15);
}
// [rows][64] bf16 tile: 128 B rows, 8 chunks
__device__ __forceinline__ int pbsw(int row, int bytein) {
    return row * 128 + ((((bytein >> 4) ^ row) & 7) << 4) + (bytein & 15);
}

// ---------------- Kernel 1: goals + goal_probs (phase A) ----------------
__global__ __launch_bounds__(256) void k_phaseA(
    const float* __restrict__ eh, const float* __restrict__ lastpos,
    const float* __restrict__ gp_w1, const float* __restrict__ gp_b1,
    const float* __restrict__ gp_w2, const float* __restrict__ gp_b2,
    const float* __restrict__ pr_w1, const float* __restrict__ pr_b1,
    const float* __restrict__ pr_w2, const float* __restrict__ pr_b2,
    float* __restrict__ goals_o, float* __restrict__ probs_o)
{
    __shared__ __align__(16) char eT[64 * 256];  // [64][128] bf16
    __shared__ __align__(16) char gT[64 * 256];  // [64][128] bf16
    __shared__ __align__(16) char pT[64 * 128];  // [64][64] bf16
    __shared__ float lgT[64 * 8];

    const int tid = threadIdx.x;
    const int lane = tid & 63;
    const int wv = tid >> 6;           // 0..3
    const int lg = lane >> 4, li = lane & 15;
    const int r0 = blockIdx.x * 64;
    const int rowbase = wv * 16;

    // stage eh -> bf16 LDS (swizzled)
    {
        int row = tid >> 2, seg = tid & 3;
        const float* src = eh + (size_t)(r0 + row) * Hn + seg * 32;
#pragma unroll
        for (int cc = 0; cc < 4; ++cc) {
            u32 p0 = (u32)f2bf(src[cc * 8 + 0]) | ((u32)f2bf(src[cc * 8 + 1]) << 16);
            u32 p1 = (u32)f2bf(src[cc * 8 + 2]) | ((u32)f2bf(src[cc * 8 + 3]) << 16);
            u32 p2 = (u32)f2bf(src[cc * 8 + 4]) | ((u32)f2bf(src[cc * 8 + 5]) << 16);
            u32 p3 = (u32)f2bf(src[cc * 8 + 6]) | ((u32)f2bf(src[cc * 8 + 7]) << 16);
            *(u32x4*)(eT + hbsw(row, seg * 64 + cc * 16)) = (u32x4){p0, p1, p2, p3};
        }
    }
    __syncthreads();

    bf16x8 Ae[4];
#pragma unroll
    for (int kc = 0; kc < 4; ++kc)
        Ae[kc] = *(const bf16x8*)(eT + hbsw(rowbase + li, kc * 64 + lg * 16));

    // g_hid = relu(eh @ gp_w1 + gp_b1)
#pragma unroll 1
    for (int nt = 0; nt < 8; ++nt) {
        int c1 = nt * 16 + li;
        f32x4 acc = {0.f, 0.f, 0.f, 0.f};
#pragma unroll
        for (int kc = 0; kc < 4; ++kc) {
            bf16x8 bfr;
#pragma unroll
            for (int j = 0; j < 8; ++j)
                bfr[j] = (__bf16)gp_w1[(size_t)(kc * 32 + lg * 8 + j) * Hn + c1];
            acc = MFMA(Ae[kc], bfr, acc);
        }
        float bias = gp_b1[c1];
#pragma unroll
        for (int r = 0; r < 4; ++r) {
            int row = rowbase + lg * 4 + r;
            float v = fmaxf(acc[r] + bias, 0.f);
            *(u16*)(gT + hbsw(row, c1 * 2)) = f2bf(v);
        }
    }
    __syncthreads();

    // goals = g_hid @ gp_w2 + gp_b2 + last_pos
    {
        bf16x8 Ag[4];
#pragma unroll
        for (int kc = 0; kc < 4; ++kc)
            Ag[kc] = *(const bf16x8*)(gT + hbsw(rowbase + li, kc * 64 + lg * 16));
        f32x4 acc = {0.f, 0.f, 0.f, 0.f};
#pragma unroll
        for (int kc = 0; kc < 4; ++kc) {
            bf16x8 bfr;
#pragma unroll
            for (int j = 0; j < 8; ++j) {
                int k = kc * 32 + lg * 8 + j;
                bfr[j] = (li < 10) ? (__bf16)gp_w2[k * 10 + li] : (__bf16)0.f;
            }
            acc = MFMA(Ag[kc], bfr, acc);
        }
        if (li < 10) {
            float b2 = gp_b2[li];
#pragma unroll
            for (int r = 0; r < 4; ++r) {
                int b = r0 + rowbase + lg * 4 + r;
                float v = acc[r] + b2 + lastpos[(size_t)b * 2 + (li & 1)];
                goals_o[(size_t)b * 10 + li] = v;
            }
        }
    }

    // p_hid = relu(eh @ pr_w1 + pr_b1)
#pragma unroll 1
    for (int nt = 0; nt < 4; ++nt) {
        int c1 = nt * 16 + li;
        f32x4 acc = {0.f, 0.f, 0.f, 0.f};
#pragma unroll
        for (int kc = 0; kc < 4; ++kc) {
            bf16x8 bfr;
#pragma unroll
            for (int j = 0; j < 8; ++j)
                bfr[j] = (__bf16)pr_w1[(size_t)(kc * 32 + lg * 8 + j) * 64 + c1];
            acc = MFMA(Ae[kc], bfr, acc);
        }
        float bias = pr_b1[c1];
#pragma unroll
        for (int r = 0; r < 4; ++r) {
            int row = rowbase + lg * 4 + r;
            float v = fmaxf(acc[r] + bias, 0.f);
            *(u16*)(pT + pbsw(row, c1 * 2)) = f2bf(v);
        }
    }
    __syncthreads();

    // logits = p_hid @ pr_w2 + pr_b2
    {
        bf16x8 Ap[2];
#pragma unroll
        for (int kc = 0; kc < 2; ++kc)
            Ap[kc] = *(const bf16x8*)(pT + pbsw(rowbase + li, kc * 64 + lg * 16));
        f32x4 acc = {0.f, 0.f, 0.f, 0.f};
#pragma unroll
        for (int kc = 0; kc < 2; ++kc) {
            bf16x8 bfr;
#pragma unroll
            for (int j = 0; j < 8; ++j) {
                int k = kc * 32 + lg * 8 + j;
                bfr[j] = (li < 5) ? (__bf16)pr_w2[k * 5 + li] : (__bf16)0.f;
            }
            acc = MFMA(Ap[kc], bfr, acc);
        }
        if (li < 5) {
            float b2 = pr_b2[li];
#pragma unroll
            for (int r = 0; r < 4; ++r) {
                int row = rowbase + lg * 4 + r;
                lgT[row * 8 + li] = acc[r] + b2;
            }
        }
    }
    __syncthreads();

    if (tid < 64) {
        int row = tid;
        float v0 = lgT[row * 8 + 0], v1 = lgT[row * 8 + 1], v2 = lgT[row * 8 + 2];
        float v3 = lgT[row * 8 + 3], v4 = lgT[row * 8 + 4];
        float mx = fmaxf(fmaxf(fmaxf(v0, v1), fmaxf(v2, v3)), v4);
        float e0 = __builtin_amdgcn_exp2f((v0 - mx) * 1.44269504f);
        float e1 = __builtin_amdgcn_exp2f((v1 - mx) * 1.44269504f);
        float e2 = __builtin_amdgcn_exp2f((v2 - mx) * 1.44269504f);
        float e3 = __builtin_amdgcn_exp2f((v3 - mx) * 1.44269504f);
        float e4 = __builtin_amdgcn_exp2f((v4 - mx) * 1.44269504f);
        float rs = __builtin_amdgcn_rcpf(e0 + e1 + e2 + e3 + e4);
        size_t ob = (size_t)(r0 + row) * 5;
        probs_o[ob + 0] = e0 * rs;
        probs_o[ob + 1] = e1 * rs;
        probs_o[ob + 2] = e2 * rs;
        probs_o[ob + 3] = e3 * rs;
        probs_o[ob + 4] = e4 * rs;
    }
}

// ---------------- Kernel 2: LSTM rollout (swapped-operand MFMA) ----------------
// 64 rows per workgroup, 512 threads (8 waves). Wave wv owns hidden cols
// [wv*16, wv*16+16) for all 4 gates. gates^T = mfma(W_frag, H_frag):
// acc col = lane&15 = batch row, acc row = lg*4+r = hidden-col offset
// -> h_new write is 4 consecutive bf16 per thread: one ds_write_b64, conflict-free.
// NOTE: plain launch_bounds(512). Adding a min-waves/EU arg makes the allocator
// cap VGPRs below the 80-reg weight fragment set -> catastrophic scratch spill
// (measured round 2: VGPR 64, +530 MB HBM scratch traffic, 365->530 us).
__global__ __launch_bounds__(512) void k_lstm(
    const float* __restrict__ eh, const float* __restrict__ ec,
    const float* __restrict__ lastpos,
    const float* __restrict__ w_ih, const float* __restrict__ w_hh,
    const float* __restrict__ b_ih, const float* __restrict__ b_hh,
    const float* __restrict__ ph_w, const float* __restrict__ ph_b,
    const float* __restrict__ goals_o, float* __restrict__ preds)
{
    __shared__ __align__(16) char hT[2][64 * 256];  // double-buffered [64][128] bf16, swizzled
    __shared__ float pos2[64 * 2];
    __shared__ float phwl[256];

    const int tid = threadIdx.x;
    const int lane = tid & 63;
    const int wv = tid >> 6;            // 0..7
    const int lg = lane >> 4, li = lane & 15;
    const int r0 = blockIdx.x * 64;

    // --- weight fragments in registers (A-operand form; same per-lane data as B-form)
    bf16x8 Wh[4][4];   // w_hh, [gate][kc]
    bf16x8 Wx[4];      // [w_ih; b_ih+b_hh; 0...], K=32
#pragma unroll
    for (int gt = 0; gt < 4; ++gt) {
        const int cg = gt * 128 + wv * 16 + li;
#pragma unroll
        for (int kc = 0; kc < 4; ++kc) {
            bf16x8 f;
#pragma unroll
            for (int j = 0; j < 8; ++j)
                f[j] = (__bf16)w_hh[(size_t)(kc * 32 + lg * 8 + j) * 512 + cg];
            Wh[gt][kc] = f;
        }
        bf16x8 fx;
#pragma unroll
        for (int j = 0; j < 8; ++j) {
            int k = lg * 8 + j;
            float v = 0.f;
            if (k < 4) v = w_ih[k * 512 + cg];
            else if (k == 4) v = b_ih[cg] + b_hh[cg];
            fx[j] = (__bf16)v;
        }
        Wx[gt] = fx;
    }

    // --- goals packed per m-tile (bf16 pair), for in-register x-fragment
    u32 gpk[4];
#pragma unroll
    for (int m = 0; m < 4; ++m) {
        int gr = r0 + m * 16 + li;
        float2 g2 = *(const float2*)(goals_o + (size_t)gr * 2);
        gpk[m] = (u32)f2bf(g2.x) | ((u32)f2bf(g2.y) << 16);
    }

    // --- stage h0 = encoder_hidden (broadcast over g) into buffer 0
    {
        int row = tid >> 3, seg = tid & 7;
        int b = (r0 + row) / 5;
        const float* src = eh + (size_t)b * Hn + seg * 16;
#pragma unroll
        for (int cp = 0; cp < 2; ++cp) {
            u32 p0 = (u32)f2bf(src[cp * 8 + 0]) | ((u32)f2bf(src[cp * 8 + 1]) << 16);
            u32 p1 = (u32)f2bf(src[cp * 8 + 2]) | ((u32)f2bf(src[cp * 8 + 3]) << 16);
            u32 p2 = (u32)f2bf(src[cp * 8 + 4]) | ((u32)f2bf(src[cp * 8 + 5]) << 16);
            u32 p3 = (u32)f2bf(src[cp * 8 + 6]) | ((u32)f2bf(src[cp * 8 + 7]) << 16);
            *(u32x4*)(hT[0] + hbsw(row, seg * 32 + cp * 16)) = (u32x4){p0, p1, p2, p3};
        }
    }
    // --- pos master copy + ph_w staging
    if (tid < 64) {
        int b = (r0 + tid) / 5;
        float2 p = *(const float2*)(lastpos + (size_t)b * 2);
        pos2[2 * tid] = p.x;
        pos2[2 * tid + 1] = p.y;
    }
    if (tid < 256) phwl[tid] = ph_w[tid];
    const float phb0 = ph_b[0], phb1 = ph_b[1];

    // --- c0 registers (f32 master): c[m][r] at (batch m*16+li, hidden col wv*16+lg*4+r)
    float c[4][4];
#pragma unroll
    for (int m = 0; m < 4; ++m) {
        int b = (r0 + m * 16 + li) / 5;
        float4 cv = *(const float4*)(ec + (size_t)b * Hn + wv * 16 + lg * 4);
        c[m][0] = cv.x; c[m][1] = cv.y; c[m][2] = cv.z; c[m][3] = cv.w;
    }

    __syncthreads();

#pragma unroll 1
    for (int t = 0; t < Tn; ++t) {
        const char* rb = hT[t & 1];
        char* wb = hT[(t & 1) ^ 1];
#pragma unroll
        for (int m = 0; m < 4; ++m) {
            // x-fragment in registers (B-operand; nonzero only for lg==0)
            float2 p2 = *(const float2*)(&pos2[(m * 16 + li) * 2]);
            u32 xw0 = (lg == 0) ? ((u32)f2bf(p2.x) | ((u32)f2bf(p2.y) << 16)) : 0u;
            u32 xw1 = (lg == 0) ? gpk[m] : 0u;
            u32 xw2 = (lg == 0) ? 0x00003F80u : 0u;   // bf16 1.0 at k=4 (bias row)
            bf16x8 xf = __builtin_bit_cast(bf16x8, (u32x4){xw0, xw1, xw2, 0u});

            f32x4 a0 = {0.f, 0.f, 0.f, 0.f}, a1 = {0.f, 0.f, 0.f, 0.f};
            f32x4 a2 = {0.f, 0.f, 0.f, 0.f}, a3 = {0.f, 0.f, 0.f, 0.f};
#pragma unroll
            for (int kc = 0; kc < 4; ++kc) {
                bf16x8 Hf = *(const bf16x8*)(rb + hbsw(m * 16 + li, kc * 64 + lg * 16));
                a0 = MFMA(Wh[0][kc], Hf, a0);
                a1 = MFMA(Wh[1][kc], Hf, a1);
                a2 = MFMA(Wh[2][kc], Hf, a2);
                a3 = MFMA(Wh[3][kc], Hf, a3);
            }
            a0 = MFMA(Wx[0], xf, a0);
            a1 = MFMA(Wx[1], xf, a1);
            a2 = MFMA(Wx[2], xf, a2);
            a3 = MFMA(Wx[3], xf, a3);

            u32 w0 = 0, w1 = 0;
#pragma unroll
            for (int r = 0; r < 4; ++r) {
                float cn = sigf(a1[r]) * c[m][r] + sigf(a0[r]) * tanhf_(a2[r]);
                c[m][r] = cn;
                float hv = sigf(a3[r]) * tanhf_(cn);
                u32 hb = (u32)f2bf(hv);
                if (r == 0) w0 = hb;
                else if (r == 1) w0 |= hb << 16;
                else if (r == 2) w1 = hb;
                else w1 |= hb << 16;
            }
            // one contiguous 8B write: row = m*16+li, cols wv*16+lg*4 .. +3
            *(u32x2*)(wb + hbsw(m * 16 + li, wv * 32 + lg * 8)) = (u32x2){w0, w1};
        }
        __syncthreads();   // h_new visible (and old-h reads complete for next write)

        // --- pos update: pos += h_new @ ph_w + ph_b
        {
            int row = tid >> 3, seg = tid & 7;
            float sx = 0.f, sy = 0.f;
#pragma unroll
            for (int cp = 0; cp < 2; ++cp) {
                u32x4 d = *(const u32x4*)(wb + hbsw(row, seg * 32 + cp * 16));
                int cb = seg * 16 + cp * 8;
#pragma unroll
                for (int j = 0; j < 4; ++j) {
                    float h0 = bf2f((u16)(d[j] & 0xFFFFu));
                    float h1 = bf2f((u16)(d[j] >> 16));
                    int cidx = cb + 2 * j;
                    sx += h0 * phwl[cidx * 2 + 0] + h1 * phwl[cidx * 2 + 2];
                    sy += h0 * phwl[cidx * 2 + 1] + h1 * phwl[cidx * 2 + 3];
                }
            }
            sx += __shfl_xor(sx, 1); sy += __shfl_xor(sy, 1);
            sx += __shfl_xor(sx, 2); sy += __shfl_xor(sy, 2);
            sx += __shfl_xor(sx, 4); sy += __shfl_xor(sy, 4);
            if (seg == 0) {
                float px = pos2[2 * row] + sx + phb0;
                float py = pos2[2 * row + 1] + sy + phb1;
                pos2[2 * row] = px;
                pos2[2 * row + 1] = py;
                size_t o = ((size_t)(r0 + row) * Tn + t) * 2;
                *(float2*)(preds + o) = make_float2(px, py);
            }
        }
        __syncthreads();   // pos2 visible for next step's x-fragment
    }
}

extern "C" void kernel_launch(void* const* d_in, const int* in_sizes, int n_in,
                              void* d_out, int out_size, void* d_ws, size_t ws_size,
                              hipStream_t stream)
{
    (void)in_sizes; (void)n_in; (void)out_size; (void)d_ws; (void)ws_size;
    const float* eh   = (const float*)d_in[0];
    const float* ec   = (const float*)d_in[1];
    const float* lp   = (const float*)d_in[2];
    const float* gpw1 = (const float*)d_in[3];
    const float* gpb1 = (const float*)d_in[4];
    const float* gpw2 = (const float*)d_in[5];
    const float* gpb2 = (const float*)d_in[6];
    const float* prw1 = (const float*)d_in[7];
    const float* prb1 = (const float*)d_in[8];
    const float* prw2 = (const float*)d_in[9];
    const float* prb2 = (const float*)d_in[10];
    const float* wih  = (const float*)d_in[11];
    const float* whh  = (const float*)d_in[12];
    const float* bih  = (const float*)d_in[13];
    const float* bhh  = (const float*)d_in[14];
    const float* phw  = (const float*)d_in[15];
    const float* phb  = (const float*)d_in[16];

    float* out = (float*)d_out;
    float* preds = out;                                            // [B,G,T,2]
    float* goals = out + (size_t)Bn * Gn * Tn * 2;                 // [B,G,2]
    float* probs = out + (size_t)Bn * Gn * Tn * 2 + (size_t)Bn * Gn * 2;  // [B,G]

    k_phaseA<<<Bn / 64, 256, 0, stream>>>(eh, lp, gpw1, gpb1, gpw2, gpb2,
                                          prw1, prb1, prw2, prb2, goals, probs);
    k_lstm<<<(Bn * Gn) / 64, 512, 0, stream>>>(eh, ec, lp, wih, whh, bih, bhh,
                                               phw, phb, goals, preds);
}

// Round 4
// 265.195 us; speedup vs baseline: 1.9163x; 1.4189x over previous
//
#include <hip/hip_runtime.h>

#define Bn 16384
#define Hn 128
#define Gn 5
#define Tn 12

typedef __attribute__((ext_vector_type(8))) __bf16 bf16x8;
typedef __attribute__((ext_vector_type(4))) float f32x4;
typedef __attribute__((ext_vector_type(4))) unsigned int u32x4;
typedef __attribute__((ext_vector_type(2))) unsigned int u32x2;
typedef unsigned int u32;
typedef unsigned short u16;

#define MFMA(a, b, c) __builtin_amdgcn_mfma_f32_16x16x32_bf16((a), (b), (c), 0, 0, 0)

__device__ __forceinline__ u16 f2bf(float f) { return __builtin_bit_cast(u16, (__bf16)f); }
__device__ __forceinline__ float bf2f(u16 h) { u32 u = ((u32)h) << 16; return __builtin_bit_cast(float, u); }
__device__ __forceinline__ u32 pk2(float a, float b) { return (u32)f2bf(a) | ((u32)f2bf(b) << 16); }
__device__ __forceinline__ float sigf(float x) {
    return __builtin_amdgcn_rcpf(1.0f + __builtin_amdgcn_exp2f(-1.44269504f * x));
}
__device__ __forceinline__ float tanhf_(float x) {
    return 1.0f - 2.0f * __builtin_amdgcn_rcpf(1.0f + __builtin_amdgcn_exp2f(2.88539008f * x));
}

// Swizzled byte offsets (chunk-XOR): [rows][128] bf16 tile, 256 B rows, 16 chunks of 16 B
__device__ __forceinline__ int hbsw(int row, int bytein) {
    return row * 256 + ((((bytein >> 4) ^ row) & 15) << 4) + (bytein & 15);
}
// [rows][64] bf16 tile: 128 B rows, 8 chunks
__device__ __forceinline__ int pbsw(int row, int bytein) {
    return row * 128 + ((((bytein >> 4) ^ row) & 7) << 4) + (bytein & 15);
}

// ---------------- Kernel 1: goals + goal_probs (phase A) ----------------
__global__ __launch_bounds__(256) void k_phaseA(
    const float* __restrict__ eh, const float* __restrict__ lastpos,
    const float* __restrict__ gp_w1, const float* __restrict__ gp_b1,
    const float* __restrict__ gp_w2, const float* __restrict__ gp_b2,
    const float* __restrict__ pr_w1, const float* __restrict__ pr_b1,
    const float* __restrict__ pr_w2, const float* __restrict__ pr_b2,
    float* __restrict__ goals_o, float* __restrict__ probs_o)
{
    __shared__ __align__(16) char eT[64 * 256];  // [64][128] bf16
    __shared__ __align__(16) char gT[64 * 256];  // [64][128] bf16
    __shared__ __align__(16) char pT[64 * 128];  // [64][64] bf16
    __shared__ float lgT[64 * 8];

    const int tid = threadIdx.x;
    const int lane = tid & 63;
    const int wv = tid >> 6;           // 0..3
    const int lg = lane >> 4, li = lane & 15;
    const int r0 = blockIdx.x * 64;
    const int rowbase = wv * 16;

    // stage eh -> bf16 LDS (swizzled)
    {
        int row = tid >> 2, seg = tid & 3;
        const float* src = eh + (size_t)(r0 + row) * Hn + seg * 32;
#pragma unroll
        for (int cc = 0; cc < 4; ++cc) {
            u32 p0 = pk2(src[cc * 8 + 0], src[cc * 8 + 1]);
            u32 p1 = pk2(src[cc * 8 + 2], src[cc * 8 + 3]);
            u32 p2 = pk2(src[cc * 8 + 4], src[cc * 8 + 5]);
            u32 p3 = pk2(src[cc * 8 + 6], src[cc * 8 + 7]);
            *(u32x4*)(eT + hbsw(row, seg * 64 + cc * 16)) = (u32x4){p0, p1, p2, p3};
        }
    }
    __syncthreads();

    bf16x8 Ae[4];
#pragma unroll
    for (int kc = 0; kc < 4; ++kc)
        Ae[kc] = *(const bf16x8*)(eT + hbsw(rowbase + li, kc * 64 + lg * 16));

    // g_hid = relu(eh @ gp_w1 + gp_b1)
#pragma unroll 1
    for (int nt = 0; nt < 8; ++nt) {
        int c1 = nt * 16 + li;
        f32x4 acc = {0.f, 0.f, 0.f, 0.f};
#pragma unroll
        for (int kc = 0; kc < 4; ++kc) {
            bf16x8 bfr;
#pragma unroll
            for (int j = 0; j < 8; ++j)
                bfr[j] = (__bf16)gp_w1[(size_t)(kc * 32 + lg * 8 + j) * Hn + c1];
            acc = MFMA(Ae[kc], bfr, acc);
        }
        float bias = gp_b1[c1];
#pragma unroll
        for (int r = 0; r < 4; ++r) {
            int row = rowbase + lg * 4 + r;
            float v = fmaxf(acc[r] + bias, 0.f);
            *(u16*)(gT + hbsw(row, c1 * 2)) = f2bf(v);
        }
    }
    __syncthreads();

    // goals = g_hid @ gp_w2 + gp_b2 + last_pos
    {
        bf16x8 Ag[4];
#pragma unroll
        for (int kc = 0; kc < 4; ++kc)
            Ag[kc] = *(const bf16x8*)(gT + hbsw(rowbase + li, kc * 64 + lg * 16));
        f32x4 acc = {0.f, 0.f, 0.f, 0.f};
#pragma unroll
        for (int kc = 0; kc < 4; ++kc) {
            bf16x8 bfr;
#pragma unroll
            for (int j = 0; j < 8; ++j) {
                int k = kc * 32 + lg * 8 + j;
                bfr[j] = (li < 10) ? (__bf16)gp_w2[k * 10 + li] : (__bf16)0.f;
            }
            acc = MFMA(Ag[kc], bfr, acc);
        }
        if (li < 10) {
            float b2 = gp_b2[li];
#pragma unroll
            for (int r = 0; r < 4; ++r) {
                int b = r0 + rowbase + lg * 4 + r;
                float v = acc[r] + b2 + lastpos[(size_t)b * 2 + (li & 1)];
                goals_o[(size_t)b * 10 + li] = v;
            }
        }
    }

    // p_hid = relu(eh @ pr_w1 + pr_b1)
#pragma unroll 1
    for (int nt = 0; nt < 4; ++nt) {
        int c1 = nt * 16 + li;
        f32x4 acc = {0.f, 0.f, 0.f, 0.f};
#pragma unroll
        for (int kc = 0; kc < 4; ++kc) {
            bf16x8 bfr;
#pragma unroll
            for (int j = 0; j < 8; ++j)
                bfr[j] = (__bf16)pr_w1[(size_t)(kc * 32 + lg * 8 + j) * 64 + c1];
            acc = MFMA(Ae[kc], bfr, acc);
        }
        float bias = pr_b1[c1];
#pragma unroll
        for (int r = 0; r < 4; ++r) {
            int row = rowbase + lg * 4 + r;
            float v = fmaxf(acc[r] + bias, 0.f);
            *(u16*)(pT + pbsw(row, c1 * 2)) = f2bf(v);
        }
    }
    __syncthreads();

    // logits = p_hid @ pr_w2 + pr_b2
    {
        bf16x8 Ap[2];
#pragma unroll
        for (int kc = 0; kc < 2; ++kc)
            Ap[kc] = *(const bf16x8*)(pT + pbsw(rowbase + li, kc * 64 + lg * 16));
        f32x4 acc = {0.f, 0.f, 0.f, 0.f};
#pragma unroll
        for (int kc = 0; kc < 2; ++kc) {
            bf16x8 bfr;
#pragma unroll
            for (int j = 0; j < 8; ++j) {
                int k = kc * 32 + lg * 8 + j;
                bfr[j] = (li < 5) ? (__bf16)pr_w2[k * 5 + li] : (__bf16)0.f;
            }
            acc = MFMA(Ap[kc], bfr, acc);
        }
        if (li < 5) {
            float b2 = pr_b2[li];
#pragma unroll
            for (int r = 0; r < 4; ++r) {
                int row = rowbase + lg * 4 + r;
                lgT[row * 8 + li] = acc[r] + b2;
            }
        }
    }
    __syncthreads();

    if (tid < 64) {
        int row = tid;
        float v0 = lgT[row * 8 + 0], v1 = lgT[row * 8 + 1], v2 = lgT[row * 8 + 2];
        float v3 = lgT[row * 8 + 3], v4 = lgT[row * 8 + 4];
        float mx = fmaxf(fmaxf(fmaxf(v0, v1), fmaxf(v2, v3)), v4);
        float e0 = __builtin_amdgcn_exp2f((v0 - mx) * 1.44269504f);
        float e1 = __builtin_amdgcn_exp2f((v1 - mx) * 1.44269504f);
        float e2 = __builtin_amdgcn_exp2f((v2 - mx) * 1.44269504f);
        float e3 = __builtin_amdgcn_exp2f((v3 - mx) * 1.44269504f);
        float e4 = __builtin_amdgcn_exp2f((v4 - mx) * 1.44269504f);
        float rs = __builtin_amdgcn_rcpf(e0 + e1 + e2 + e3 + e4);
        size_t ob = (size_t)(r0 + row) * 5;
        probs_o[ob + 0] = e0 * rs;
        probs_o[ob + 1] = e1 * rs;
        probs_o[ob + 2] = e2 * rs;
        probs_o[ob + 3] = e3 * rs;
        probs_o[ob + 4] = e4 * rs;
    }
}

// ---------------- Kernel 2: LSTM rollout ----------------
// 64 rows per workgroup, 512 threads (8 waves). Wave wv owns hidden cols
// [wv*16, wv*16+16) for all 4 gates. gates^T = mfma(W_frag, H_frag).
// pos update fused as 4 extra MFMAs per m-tile (A = ph_w columns in rows 0,1)
// reusing the already-loaded Hf fragments -> pos lives in registers of lg==0
// lanes, redundantly per wave. ONE barrier per step (double-buffered h tile;
// reads precede writes in program order, so post-write barrier covers both).
// NOTE: plain launch_bounds(512): a min-waves arg makes the allocator cap
// below the ~100-reg persistent set -> catastrophic spill (measured R2).
__global__ __launch_bounds__(512) void k_lstm(
    const float* __restrict__ eh, const float* __restrict__ ec,
    const float* __restrict__ lastpos,
    const float* __restrict__ w_ih, const float* __restrict__ w_hh,
    const float* __restrict__ b_ih, const float* __restrict__ b_hh,
    const float* __restrict__ ph_w, const float* __restrict__ ph_b,
    const float* __restrict__ goals_o, float* __restrict__ preds)
{
    __shared__ __align__(16) char hT[2][64 * 256];  // double-buffered [64][128] bf16, swizzled

    const int tid = threadIdx.x;
    const int lane = tid & 63;
    const int wv = tid >> 6;            // 0..7
    const int lg = lane >> 4, li = lane & 15;
    const int r0 = blockIdx.x * 64;

    // --- weight fragments in registers
    bf16x8 Wh[4][4];   // w_hh, [gate][kc]
    bf16x8 Wx[4];      // [w_ih rows 0..3; b_ih+b_hh at k=4; 0...], K=32
#pragma unroll
    for (int gt = 0; gt < 4; ++gt) {
        const int cg = gt * 128 + wv * 16 + li;
#pragma unroll
        for (int kc = 0; kc < 4; ++kc) {
            bf16x8 f;
#pragma unroll
            for (int j = 0; j < 8; ++j)
                f[j] = (__bf16)w_hh[(size_t)(kc * 32 + lg * 8 + j) * 512 + cg];
            Wh[gt][kc] = f;
        }
        bf16x8 fx;
#pragma unroll
        for (int j = 0; j < 8; ++j) {
            int k = lg * 8 + j;
            float v = 0.f;
            if (k < 4) v = w_ih[k * 512 + cg];
            else if (k == 4) v = b_ih[cg] + b_hh[cg];
            fx[j] = (__bf16)v;
        }
        Wx[gt] = fx;
    }

    // --- ph_w A-fragments: row 0 = ph_w[:,0], row 1 = ph_w[:,1], rows>=2 dont-care
    // (pacc rows >=2 land in pacc[r>=2] of lg==0 or any pacc of lg>0 -- never read)
    bf16x8 php[4];
#pragma unroll
    for (int kc = 0; kc < 4; ++kc) {
        u32 w[4];
#pragma unroll
        for (int jp = 0; jp < 4; ++jp) {
            int k = kc * 32 + lg * 8 + jp * 2;
            u32 xw = pk2(ph_w[k * 2 + 0], ph_w[k * 2 + 2]);
            u32 yw = pk2(ph_w[k * 2 + 1], ph_w[k * 2 + 3]);
            w[jp] = (li == 0) ? xw : yw;
        }
        php[kc] = __builtin_bit_cast(bf16x8, (u32x4){w[0], w[1], w[2], w[3]});
    }
    const float phb0 = ph_b[0], phb1 = ph_b[1];

    // --- goals packed per m-tile; pos master (valid in lg==0 lanes, junk elsewhere ok)
    u32 gpk[4];
    float px[4], py[4];
#pragma unroll
    for (int m = 0; m < 4; ++m) {
        int gr = r0 + m * 16 + li;
        float2 g2 = *(const float2*)(goals_o + (size_t)gr * 2);
        gpk[m] = pk2(g2.x, g2.y);
        float2 p = *(const float2*)(lastpos + (size_t)(gr / 5) * 2);
        px[m] = p.x; py[m] = p.y;
    }

    // --- hoisted swizzled LDS offsets (loop-invariant)
    const int ro0 = hbsw(li, 0 + lg * 16);
    const int ro1 = hbsw(li, 64 + lg * 16);
    const int ro2 = hbsw(li, 128 + lg * 16);
    const int ro3 = hbsw(li, 192 + lg * 16);
    const int wo  = hbsw(li, wv * 32 + lg * 8);

    // --- stage h0 = encoder_hidden (broadcast over g) into buffer 0
    {
        int row = tid >> 3, seg = tid & 7;
        int b = (r0 + row) / 5;
        const float* src = eh + (size_t)b * Hn + seg * 16;
#pragma unroll
        for (int cp = 0; cp < 2; ++cp) {
            u32 p0 = pk2(src[cp * 8 + 0], src[cp * 8 + 1]);
            u32 p1 = pk2(src[cp * 8 + 2], src[cp * 8 + 3]);
            u32 p2 = pk2(src[cp * 8 + 4], src[cp * 8 + 5]);
            u32 p3 = pk2(src[cp * 8 + 6], src[cp * 8 + 7]);
            *(u32x4*)(hT[0] + hbsw(row, seg * 32 + cp * 16)) = (u32x4){p0, p1, p2, p3};
        }
    }

    // --- c0 registers (f32 master): c[m][r] at (batch m*16+li, hidden col wv*16+lg*4+r)
    float c[4][4];
#pragma unroll
    for (int m = 0; m < 4; ++m) {
        int b = (r0 + m * 16 + li) / 5;
        float4 cv = *(const float4*)(ec + (size_t)b * Hn + wv * 16 + lg * 4);
        c[m][0] = cv.x; c[m][1] = cv.y; c[m][2] = cv.z; c[m][3] = cv.w;
    }

    __syncthreads();

#pragma unroll 1
    for (int t = 0; t < Tn; ++t) {
        const char* rbp = hT[0] + (t & 1) * 16384;
        char* wbp = hT[0] + ((t & 1) ^ 1) * 16384;
#pragma unroll
        for (int m = 0; m < 4; ++m) {
            const int mo = m * 4096;
            bf16x8 H0 = *(const bf16x8*)(rbp + ro0 + mo);
            bf16x8 H1 = *(const bf16x8*)(rbp + ro1 + mo);
            bf16x8 H2 = *(const bf16x8*)(rbp + ro2 + mo);
            bf16x8 H3 = *(const bf16x8*)(rbp + ro3 + mo);

            f32x4 a0 = {0.f, 0.f, 0.f, 0.f}, a1 = {0.f, 0.f, 0.f, 0.f};
            f32x4 a2 = {0.f, 0.f, 0.f, 0.f}, a3 = {0.f, 0.f, 0.f, 0.f};
            a0 = MFMA(Wh[0][0], H0, a0); a1 = MFMA(Wh[1][0], H0, a1);
            a2 = MFMA(Wh[2][0], H0, a2); a3 = MFMA(Wh[3][0], H0, a3);
            a0 = MFMA(Wh[0][1], H1, a0); a1 = MFMA(Wh[1][1], H1, a1);
            a2 = MFMA(Wh[2][1], H1, a2); a3 = MFMA(Wh[3][1], H1, a3);
            a0 = MFMA(Wh[0][2], H2, a0); a1 = MFMA(Wh[1][2], H2, a1);
            a2 = MFMA(Wh[2][2], H2, a2); a3 = MFMA(Wh[3][2], H2, a3);
            a0 = MFMA(Wh[0][3], H3, a0); a1 = MFMA(Wh[1][3], H3, a1);
            a2 = MFMA(Wh[2][3], H3, a2); a3 = MFMA(Wh[3][3], H3, a3);

            if (t > 0) {
                // pos_t = pos_{t-1} + h_t @ ph_w  (valid in lg==0 lanes)
                f32x4 pacc = {0.f, 0.f, 0.f, 0.f};
                pacc = MFMA(php[0], H0, pacc);
                pacc = MFMA(php[1], H1, pacc);
                pacc = MFMA(php[2], H2, pacc);
                pacc = MFMA(php[3], H3, pacc);
                px[m] += pacc[0] + phb0;
                py[m] += pacc[1] + phb1;
                if (wv == m && lg == 0) {
                    size_t o = ((size_t)(r0 + m * 16 + li) * Tn + (t - 1)) * 2;
                    *(float2*)(preds + o) = make_float2(px[m], py[m]);
                }
            }

            // x-fragment: rows k=0..4 = [px,py,gx,gy,1]; lanes lg>0 supply k>=8
            // whose Wx rows are zero, so their (junk) values are harmless.
            bf16x8 xf = __builtin_bit_cast(bf16x8,
                (u32x4){pk2(px[m], py[m]), gpk[m], 0x00003F80u, 0u});
            a0 = MFMA(Wx[0], xf, a0);
            a1 = MFMA(Wx[1], xf, a1);
            a2 = MFMA(Wx[2], xf, a2);
            a3 = MFMA(Wx[3], xf, a3);

            u32 w0, w1;
            {
                float cn0 = sigf(a1[0]) * c[m][0] + sigf(a0[0]) * tanhf_(a2[0]);
                float cn1 = sigf(a1[1]) * c[m][1] + sigf(a0[1]) * tanhf_(a2[1]);
                float cn2 = sigf(a1[2]) * c[m][2] + sigf(a0[2]) * tanhf_(a2[2]);
                float cn3 = sigf(a1[3]) * c[m][3] + sigf(a0[3]) * tanhf_(a2[3]);
                c[m][0] = cn0; c[m][1] = cn1; c[m][2] = cn2; c[m][3] = cn3;
                float h0 = sigf(a3[0]) * tanhf_(cn0);
                float h1 = sigf(a3[1]) * tanhf_(cn1);
                float h2 = sigf(a3[2]) * tanhf_(cn2);
                float h3 = sigf(a3[3]) * tanhf_(cn3);
                w0 = pk2(h0, h1);
                w1 = pk2(h2, h3);
            }
            *(u32x2*)(wbp + wo + mo) = (u32x2){w0, w1};
        }
        __syncthreads();   // h_new visible; old-buffer reads all done pre-barrier
    }

    // --- epilogue: pos_12 from h_12 (in buffer 0 since Tn even)
    if (wv < 4) {
        const int m = wv;
        const char* rbp = hT[0];
        const int mo = m * 4096;
        bf16x8 H0 = *(const bf16x8*)(rbp + ro0 + mo);
        bf16x8 H1 = *(const bf16x8*)(rbp + ro1 + mo);
        bf16x8 H2 = *(const bf16x8*)(rbp + ro2 + mo);
        bf16x8 H3 = *(const bf16x8*)(rbp + ro3 + mo);
        f32x4 pacc = {0.f, 0.f, 0.f, 0.f};
        pacc = MFMA(php[0], H0, pacc);
        pacc = MFMA(php[1], H1, pacc);
        pacc = MFMA(php[2], H2, pacc);
        pacc = MFMA(php[3], H3, pacc);
        if (lg == 0) {
            float fx = px[m] + pacc[0] + phb0;
            float fy = py[m] + pacc[1] + phb1;
            size_t o = ((size_t)(r0 + m * 16 + li) * Tn + (Tn - 1)) * 2;
            *(float2*)(preds + o) = make_float2(fx, fy);
        }
    }
}

extern "C" void kernel_launch(void* const* d_in, const int* in_sizes, int n_in,
                              void* d_out, int out_size, void* d_ws, size_t ws_size,
                              hipStream_t stream)
{
    (void)in_sizes; (void)n_in; (void)out_size; (void)d_ws; (void)ws_size;
    const float* eh   = (const float*)d_in[0];
    const float* ec   = (const float*)d_in[1];
    const float* lp   = (const float*)d_in[2];
    const float* gpw1 = (const float*)d_in[3];
    const float* gpb1 = (const float*)d_in[4];
    const float* gpw2 = (const float*)d_in[5];
    const float* gpb2 = (const float*)d_in[6];
    const float* prw1 = (const float*)d_in[7];
    const float* prb1 = (const float*)d_in[8];
    const float* prw2 = (const float*)d_in[9];
    const float* prb2 = (const float*)d_in[10];
    const float* wih  = (const float*)d_in[11];
    const float* whh  = (const float*)d_in[12];
    const float* bih  = (const float*)d_in[13];
    const float* bhh  = (const float*)d_in[14];
    const float* phw  = (const float*)d_in[15];
    const float* phb  = (const float*)d_in[16];

    float* out = (float*)d_out;
    float* preds = out;                                            // [B,G,T,2]
    float* goals = out + (size_t)Bn * Gn * Tn * 2;                 // [B,G,2]
    float* probs = out + (size_t)Bn * Gn * Tn * 2 + (size_t)Bn * Gn * 2;  // [B,G]

    k_phaseA<<<Bn / 64, 256, 0, stream>>>(eh, lp, gpw1, gpb1, gpw2, gpb2,
                                          prw1, prb1, prw2, prb2, goals, probs);
    k_lstm<<<(Bn * Gn) / 64, 512, 0, stream>>>(eh, ec, lp, wih, whh, bih, bhh,
                                               phw, phb, goals, preds);
}

// Round 5
// 246.511 us; speedup vs baseline: 2.0616x; 1.0758x over previous
//
#include <hip/hip_runtime.h>

#define Bn 16384
#define Hn 128
#define Gn 5
#define Tn 12

typedef __attribute__((ext_vector_type(8))) __bf16 bf16x8;
typedef __attribute__((ext_vector_type(4))) float f32x4;
typedef __attribute__((ext_vector_type(4))) unsigned int u32x4;
typedef __attribute__((ext_vector_type(2))) unsigned int u32x2;
typedef unsigned int u32;
typedef unsigned short u16;

#define MFMA(a, b, c) __builtin_amdgcn_mfma_f32_16x16x32_bf16((a), (b), (c), 0, 0, 0)

__device__ __forceinline__ u16 f2bf(float f) { return __builtin_bit_cast(u16, (__bf16)f); }
__device__ __forceinline__ u32 pk2(float a, float b) { return (u32)f2bf(a) | ((u32)f2bf(b) << 16); }

// Swizzled byte offsets (chunk-XOR): [rows][128] bf16 tile, 256 B rows, 16 chunks of 16 B
__device__ __forceinline__ int hbsw(int row, int bytein) {
    return row * 256 + ((((bytein >> 4) ^ row) & 15) << 4) + (bytein & 15);
}
// [rows][64] bf16 tile: 128 B rows, 8 chunks
__device__ __forceinline__ int pbsw(int row, int bytein) {
    return row * 128 + ((((bytein >> 4) ^ row) & 7) << 4) + (bytein & 15);
}

// ---------------- Kernel 1: goals + goal_probs (phase A) ----------------
__global__ __launch_bounds__(256) void k_phaseA(
    const float* __restrict__ eh, const float* __restrict__ lastpos,
    const float* __restrict__ gp_w1, const float* __restrict__ gp_b1,
    const float* __restrict__ gp_w2, const float* __restrict__ gp_b2,
    const float* __restrict__ pr_w1, const float* __restrict__ pr_b1,
    const float* __restrict__ pr_w2, const float* __restrict__ pr_b2,
    float* __restrict__ goals_o, float* __restrict__ probs_o)
{
    __shared__ __align__(16) char eT[64 * 256];  // [64][128] bf16
    __shared__ __align__(16) char gT[64 * 256];  // [64][128] bf16
    __shared__ __align__(16) char pT[64 * 128];  // [64][64] bf16
    __shared__ float lgT[64 * 8];

    const int tid = threadIdx.x;
    const int lane = tid & 63;
    const int wv = tid >> 6;           // 0..3
    const int lg = lane >> 4, li = lane & 15;
    const int r0 = blockIdx.x * 64;
    const int rowbase = wv * 16;

    // stage eh -> bf16 LDS (swizzled)
    {
        int row = tid >> 2, seg = tid & 3;
        const float* src = eh + (size_t)(r0 + row) * Hn + seg * 32;
#pragma unroll
        for (int cc = 0; cc < 4; ++cc) {
            u32 p0 = pk2(src[cc * 8 + 0], src[cc * 8 + 1]);
            u32 p1 = pk2(src[cc * 8 + 2], src[cc * 8 + 3]);
            u32 p2 = pk2(src[cc * 8 + 4], src[cc * 8 + 5]);
            u32 p3 = pk2(src[cc * 8 + 6], src[cc * 8 + 7]);
            *(u32x4*)(eT + hbsw(row, seg * 64 + cc * 16)) = (u32x4){p0, p1, p2, p3};
        }
    }
    __syncthreads();

    bf16x8 Ae[4];
#pragma unroll
    for (int kc = 0; kc < 4; ++kc)
        Ae[kc] = *(const bf16x8*)(eT + hbsw(rowbase + li, kc * 64 + lg * 16));

    // g_hid = relu(eh @ gp_w1 + gp_b1)
#pragma unroll 1
    for (int nt = 0; nt < 8; ++nt) {
        int c1 = nt * 16 + li;
        f32x4 acc = {0.f, 0.f, 0.f, 0.f};
#pragma unroll
        for (int kc = 0; kc < 4; ++kc) {
            bf16x8 bfr;
#pragma unroll
            for (int j = 0; j < 8; ++j)
                bfr[j] = (__bf16)gp_w1[(size_t)(kc * 32 + lg * 8 + j) * Hn + c1];
            acc = MFMA(Ae[kc], bfr, acc);
        }
        float bias = gp_b1[c1];
#pragma unroll
        for (int r = 0; r < 4; ++r) {
            int row = rowbase + lg * 4 + r;
            float v = fmaxf(acc[r] + bias, 0.f);
            *(u16*)(gT + hbsw(row, c1 * 2)) = f2bf(v);
        }
    }
    __syncthreads();

    // goals = g_hid @ gp_w2 + gp_b2 + last_pos
    {
        bf16x8 Ag[4];
#pragma unroll
        for (int kc = 0; kc < 4; ++kc)
            Ag[kc] = *(const bf16x8*)(gT + hbsw(rowbase + li, kc * 64 + lg * 16));
        f32x4 acc = {0.f, 0.f, 0.f, 0.f};
#pragma unroll
        for (int kc = 0; kc < 4; ++kc) {
            bf16x8 bfr;
#pragma unroll
            for (int j = 0; j < 8; ++j) {
                int k = kc * 32 + lg * 8 + j;
                bfr[j] = (li < 10) ? (__bf16)gp_w2[k * 10 + li] : (__bf16)0.f;
            }
            acc = MFMA(Ag[kc], bfr, acc);
        }
        if (li < 10) {
            float b2 = gp_b2[li];
#pragma unroll
            for (int r = 0; r < 4; ++r) {
                int b = r0 + rowbase + lg * 4 + r;
                float v = acc[r] + b2 + lastpos[(size_t)b * 2 + (li & 1)];
                goals_o[(size_t)b * 10 + li] = v;
            }
        }
    }

    // p_hid = relu(eh @ pr_w1 + pr_b1)
#pragma unroll 1
    for (int nt = 0; nt < 4; ++nt) {
        int c1 = nt * 16 + li;
        f32x4 acc = {0.f, 0.f, 0.f, 0.f};
#pragma unroll
        for (int kc = 0; kc < 4; ++kc) {
            bf16x8 bfr;
#pragma unroll
            for (int j = 0; j < 8; ++j)
                bfr[j] = (__bf16)pr_w1[(size_t)(kc * 32 + lg * 8 + j) * 64 + c1];
            acc = MFMA(Ae[kc], bfr, acc);
        }
        float bias = pr_b1[c1];
#pragma unroll
        for (int r = 0; r < 4; ++r) {
            int row = rowbase + lg * 4 + r;
            float v = fmaxf(acc[r] + bias, 0.f);
            *(u16*)(pT + pbsw(row, c1 * 2)) = f2bf(v);
        }
    }
    __syncthreads();

    // logits = p_hid @ pr_w2 + pr_b2
    {
        bf16x8 Ap[2];
#pragma unroll
        for (int kc = 0; kc < 2; ++kc)
            Ap[kc] = *(const bf16x8*)(pT + pbsw(rowbase + li, kc * 64 + lg * 16));
        f32x4 acc = {0.f, 0.f, 0.f, 0.f};
#pragma unroll
        for (int kc = 0; kc < 2; ++kc) {
            bf16x8 bfr;
#pragma unroll
            for (int j = 0; j < 8; ++j) {
                int k = kc * 32 + lg * 8 + j;
                bfr[j] = (li < 5) ? (__bf16)pr_w2[k * 5 + li] : (__bf16)0.f;
            }
            acc = MFMA(Ap[kc], bfr, acc);
        }
        if (li < 5) {
            float b2 = pr_b2[li];
#pragma unroll
            for (int r = 0; r < 4; ++r) {
                int row = rowbase + lg * 4 + r;
                lgT[row * 8 + li] = acc[r] + b2;
            }
        }
    }
    __syncthreads();

    if (tid < 64) {
        int row = tid;
        float v0 = lgT[row * 8 + 0], v1 = lgT[row * 8 + 1], v2 = lgT[row * 8 + 2];
        float v3 = lgT[row * 8 + 3], v4 = lgT[row * 8 + 4];
        float mx = fmaxf(fmaxf(fmaxf(v0, v1), fmaxf(v2, v3)), v4);
        float e0 = __builtin_amdgcn_exp2f((v0 - mx) * 1.44269504f);
        float e1 = __builtin_amdgcn_exp2f((v1 - mx) * 1.44269504f);
        float e2 = __builtin_amdgcn_exp2f((v2 - mx) * 1.44269504f);
        float e3 = __builtin_amdgcn_exp2f((v3 - mx) * 1.44269504f);
        float e4 = __builtin_amdgcn_exp2f((v4 - mx) * 1.44269504f);
        float rs = __builtin_amdgcn_rcpf(e0 + e1 + e2 + e3 + e4);
        size_t ob = (size_t)(r0 + row) * 5;
        probs_o[ob + 0] = e0 * rs;
        probs_o[ob + 1] = e1 * rs;
        probs_o[ob + 2] = e2 * rs;
        probs_o[ob + 3] = e3 * rs;
        probs_o[ob + 4] = e4 * rs;
    }
}

// ---------------- Kernel 2: LSTM rollout ----------------
// 160 rows per workgroup (10 m-tiles), 512 threads (8 waves), 512 blocks =
// exactly 2 sequential blocks per CU. Barrier events per CU: 24 (was 60);
// 10 independent m-chains per step fill the pipes between barriers.
// Activation scales folded into weights: i,f,o gates pre-scaled by -log2e,
// g gate by +2*log2e, so sigmoid = rcp(1+exp2(a)), tanh = 1-2*rcp(1+exp2(a)).
// NOTE: plain launch_bounds(512): a min-waves arg makes the allocator cap
// below the persistent register set -> catastrophic spill (measured R2).
__global__ __launch_bounds__(512) void k_lstm(
    const float* __restrict__ eh, const float* __restrict__ ec,
    const float* __restrict__ lastpos,
    const float* __restrict__ w_ih, const float* __restrict__ w_hh,
    const float* __restrict__ b_ih, const float* __restrict__ b_hh,
    const float* __restrict__ ph_w, const float* __restrict__ ph_b,
    const float* __restrict__ goals_o, float* __restrict__ preds)
{
#define MT 10                       // m-tiles per block
#define ROWS (MT * 16)              // 160
#define BUFB (ROWS * 256)           // 40960 B per buffer
    __shared__ __align__(16) char hT[2][BUFB];  // double-buffered [160][128] bf16, swizzled

    const int tid = threadIdx.x;
    const int lane = tid & 63;
    const int wv = tid >> 6;            // 0..7
    const int lg = lane >> 4, li = lane & 15;
    const int r0 = blockIdx.x * ROWS;

    const float NL = -1.44269504f;      // -log2e (i,f,o)
    const float PG = 2.88539008f;       // +2*log2e (g, and tanh(c) argument)

    // --- weight fragments in registers (scale-folded)
    bf16x8 Wh[4][4];   // w_hh, [gate][kc]
    bf16x8 Wx[4];      // [w_ih rows 0..3; b_ih+b_hh at k=4; 0...], K=32
#pragma unroll
    for (int gt = 0; gt < 4; ++gt) {
        const float s = (gt == 2) ? PG : NL;
        const int cg = gt * 128 + wv * 16 + li;
#pragma unroll
        for (int kc = 0; kc < 4; ++kc) {
            bf16x8 f;
#pragma unroll
            for (int j = 0; j < 8; ++j)
                f[j] = (__bf16)(w_hh[(size_t)(kc * 32 + lg * 8 + j) * 512 + cg] * s);
            Wh[gt][kc] = f;
        }
        bf16x8 fx;
#pragma unroll
        for (int j = 0; j < 8; ++j) {
            int k = lg * 8 + j;
            float v = 0.f;
            if (k < 4) v = w_ih[k * 512 + cg] * s;
            else if (k == 4) v = (b_ih[cg] + b_hh[cg]) * s;
            fx[j] = (__bf16)v;
        }
        Wx[gt] = fx;
    }

    // --- ph_w A-fragments (unscaled): row 0 = ph_w[:,0], row 1 = ph_w[:,1]
    bf16x8 php[4];
#pragma unroll
    for (int kc = 0; kc < 4; ++kc) {
        u32 w[4];
#pragma unroll
        for (int jp = 0; jp < 4; ++jp) {
            int k = kc * 32 + lg * 8 + jp * 2;
            u32 xw = pk2(ph_w[k * 2 + 0], ph_w[k * 2 + 2]);
            u32 yw = pk2(ph_w[k * 2 + 1], ph_w[k * 2 + 3]);
            w[jp] = (li == 0) ? xw : yw;
        }
        php[kc] = __builtin_bit_cast(bf16x8, (u32x4){w[0], w[1], w[2], w[3]});
    }
    const float phb0 = ph_b[0], phb1 = ph_b[1];

    // --- goals packed per m-tile; pos master (valid in lg==0 lanes, junk elsewhere ok)
    u32 gpk[MT];
    float px[MT], py[MT];
#pragma unroll
    for (int m = 0; m < MT; ++m) {
        int gr = r0 + m * 16 + li;
        float2 g2 = *(const float2*)(goals_o + (size_t)gr * 2);
        gpk[m] = pk2(g2.x, g2.y);
        float2 p = *(const float2*)(lastpos + (size_t)(gr / 5) * 2);
        px[m] = p.x; py[m] = p.y;
    }

    // --- hoisted swizzled LDS offsets (loop-invariant)
    const int ro0 = hbsw(li, 0 + lg * 16);
    const int ro1 = hbsw(li, 64 + lg * 16);
    const int ro2 = hbsw(li, 128 + lg * 16);
    const int ro3 = hbsw(li, 192 + lg * 16);
    const int wo  = hbsw(li, wv * 32 + lg * 8);

    // --- stage h0 = encoder_hidden (broadcast over g) into buffer 0
#pragma unroll
    for (int it = 0; it < 5; ++it) {
        int chunk = tid + it * 512;          // 2560 chunks of 16 B
        int row = chunk >> 4, seg = chunk & 15;
        const float* src = eh + (size_t)((r0 + row) / 5) * Hn + seg * 8;
        u32 p0 = pk2(src[0], src[1]);
        u32 p1 = pk2(src[2], src[3]);
        u32 p2 = pk2(src[4], src[5]);
        u32 p3 = pk2(src[6], src[7]);
        *(u32x4*)(hT[0] + hbsw(row, seg * 16)) = (u32x4){p0, p1, p2, p3};
    }

    // --- c0 registers (f32 master): c[m][r] at (batch m*16+li, hidden col wv*16+lg*4+r)
    f32x4 c[MT];
#pragma unroll
    for (int m = 0; m < MT; ++m) {
        int b = (r0 + m * 16 + li) / 5;
        float4 cv = *(const float4*)(ec + (size_t)b * Hn + wv * 16 + lg * 4);
        c[m] = (f32x4){cv.x, cv.y, cv.z, cv.w};
    }

    __syncthreads();

#pragma unroll 1
    for (int t = 0; t < Tn; ++t) {
        const char* rbp = hT[0] + (t & 1) * BUFB;
        char* wbp = hT[0] + ((t & 1) ^ 1) * BUFB;
#pragma unroll
        for (int m = 0; m < MT; ++m) {
            const int mo = m * 4096;
            bf16x8 H0 = *(const bf16x8*)(rbp + ro0 + mo);
            bf16x8 H1 = *(const bf16x8*)(rbp + ro1 + mo);
            bf16x8 H2 = *(const bf16x8*)(rbp + ro2 + mo);
            bf16x8 H3 = *(const bf16x8*)(rbp + ro3 + mo);

            f32x4 a0 = {0.f, 0.f, 0.f, 0.f}, a1 = {0.f, 0.f, 0.f, 0.f};
            f32x4 a2 = {0.f, 0.f, 0.f, 0.f}, a3 = {0.f, 0.f, 0.f, 0.f};
            a0 = MFMA(Wh[0][0], H0, a0); a1 = MFMA(Wh[1][0], H0, a1);
            a2 = MFMA(Wh[2][0], H0, a2); a3 = MFMA(Wh[3][0], H0, a3);
            a0 = MFMA(Wh[0][1], H1, a0); a1 = MFMA(Wh[1][1], H1, a1);
            a2 = MFMA(Wh[2][1], H1, a2); a3 = MFMA(Wh[3][1], H1, a3);
            a0 = MFMA(Wh[0][2], H2, a0); a1 = MFMA(Wh[1][2], H2, a1);
            a2 = MFMA(Wh[2][2], H2, a2); a3 = MFMA(Wh[3][2], H2, a3);
            a0 = MFMA(Wh[0][3], H3, a0); a1 = MFMA(Wh[1][3], H3, a1);
            a2 = MFMA(Wh[2][3], H3, a2); a3 = MFMA(Wh[3][3], H3, a3);

            if (t > 0) {
                // pos_t = pos_{t-1} + h_t @ ph_w  (valid in lg==0 lanes)
                f32x4 pacc = {0.f, 0.f, 0.f, 0.f};
                pacc = MFMA(php[0], H0, pacc);
                pacc = MFMA(php[1], H1, pacc);
                pacc = MFMA(php[2], H2, pacc);
                pacc = MFMA(php[3], H3, pacc);
                px[m] += pacc[0] + phb0;
                py[m] += pacc[1] + phb1;
                if (((m & 7) == wv) && lg == 0) {
                    size_t o = ((size_t)(r0 + m * 16 + li) * Tn + (t - 1)) * 2;
                    *(float2*)(preds + o) = make_float2(px[m], py[m]);
                }
            }

            // x-fragment: rows k=0..4 = [px,py,gx,gy,1]; lanes lg>0 supply k>=8
            // whose Wx rows are zero, so their (junk) values are harmless.
            bf16x8 xf = __builtin_bit_cast(bf16x8,
                (u32x4){pk2(px[m], py[m]), gpk[m], 0x00003F80u, 0u});
            a0 = MFMA(Wx[0], xf, a0);
            a1 = MFMA(Wx[1], xf, a1);
            a2 = MFMA(Wx[2], xf, a2);
            a3 = MFMA(Wx[3], xf, a3);

            u32 w0, w1;
            {
                // scale-folded activations: si/sf/so = rcp(1+exp2(a)),
                // tg = 1-2*rcp(1+exp2(a)), tanh(cn) = 1-2*rcp(1+exp2(PG*cn))
                float hvv[4];
#pragma unroll
                for (int r = 0; r < 4; ++r) {
                    float si = __builtin_amdgcn_rcpf(1.0f + __builtin_amdgcn_exp2f(a0[r]));
                    float sf = __builtin_amdgcn_rcpf(1.0f + __builtin_amdgcn_exp2f(a1[r]));
                    float tg = 1.0f - 2.0f * __builtin_amdgcn_rcpf(1.0f + __builtin_amdgcn_exp2f(a2[r]));
                    float so = __builtin_amdgcn_rcpf(1.0f + __builtin_amdgcn_exp2f(a3[r]));
                    float cn = sf * c[m][r] + si * tg;
                    c[m][r] = cn;
                    float tc = 1.0f - 2.0f * __builtin_amdgcn_rcpf(1.0f + __builtin_amdgcn_exp2f(PG * cn));
                    hvv[r] = so * tc;
                }
                w0 = pk2(hvv[0], hvv[1]);
                w1 = pk2(hvv[2], hvv[3]);
            }
            *(u32x2*)(wbp + wo + mo) = (u32x2){w0, w1};
        }
        __syncthreads();   // h_new visible; old-buffer reads all done pre-barrier
    }

    // --- epilogue: pos_T from h_T (in buffer 0 since Tn even)
#pragma unroll
    for (int m = 0; m < MT; ++m) {
        if ((m & 7) != wv) continue;
        const char* rbp = hT[0];
        const int mo = m * 4096;
        bf16x8 H0 = *(const bf16x8*)(rbp + ro0 + mo);
        bf16x8 H1 = *(const bf16x8*)(rbp + ro1 + mo);
        bf16x8 H2 = *(const bf16x8*)(rbp + ro2 + mo);
        bf16x8 H3 = *(const bf16x8*)(rbp + ro3 + mo);
        f32x4 pacc = {0.f, 0.f, 0.f, 0.f};
        pacc = MFMA(php[0], H0, pacc);
        pacc = MFMA(php[1], H1, pacc);
        pacc = MFMA(php[2], H2, pacc);
        pacc = MFMA(php[3], H3, pacc);
        if (lg == 0) {
            float fx = px[m] + pacc[0] + phb0;
            float fy = py[m] + pacc[1] + phb1;
            size_t o = ((size_t)(r0 + m * 16 + li) * Tn + (Tn - 1)) * 2;
            *(float2*)(preds + o) = make_float2(fx, fy);
        }
    }
#undef MT
#undef ROWS
#undef BUFB
}

extern "C" void kernel_launch(void* const* d_in, const int* in_sizes, int n_in,
                              void* d_out, int out_size, void* d_ws, size_t ws_size,
                              hipStream_t stream)
{
    (void)in_sizes; (void)n_in; (void)out_size; (void)d_ws; (void)ws_size;
    const float* eh   = (const float*)d_in[0];
    const float* ec   = (const float*)d_in[1];
    const float* lp   = (const float*)d_in[2];
    const float* gpw1 = (const float*)d_in[3];
    const float* gpb1 = (const float*)d_in[4];
    const float* gpw2 = (const float*)d_in[5];
    const float* gpb2 = (const float*)d_in[6];
    const float* prw1 = (const float*)d_in[7];
    const float* prb1 = (const float*)d_in[8];
    const float* prw2 = (const float*)d_in[9];
    const float* prb2 = (const float*)d_in[10];
    const float* wih  = (const float*)d_in[11];
    const float* whh  = (const float*)d_in[12];
    const float* bih  = (const float*)d_in[13];
    const float* bhh  = (const float*)d_in[14];
    const float* phw  = (const float*)d_in[15];
    const float* phb  = (const float*)d_in[16];

    float* out = (float*)d_out;
    float* preds = out;                                            // [B,G,T,2]
    float* goals = out + (size_t)Bn * Gn * Tn * 2;                 // [B,G,2]
    float* probs = out + (size_t)Bn * Gn * Tn * 2 + (size_t)Bn * Gn * 2;  // [B,G]

    k_phaseA<<<Bn / 64, 256, 0, stream>>>(eh, lp, gpw1, gpb1, gpw2, gpb2,
                                          prw1, prb1, prw2, prb2, goals, probs);
    k_lstm<<<(Bn * Gn) / 160, 512, 0, stream>>>(eh, ec, lp, wih, whh, bih, bhh,
                                                phw, phb, goals, preds);
}